// Round 1
// baseline (8052.973 us; speedup 1.0000x reference)
//
#include <hip/hip_runtime.h>
#include <math.h>

#define NL 4096      // 2*N_VARS literals
#define NV 2048      // N_VARS
#define NC 8192      // N_CLAUSES
#define DIM 128
#define NG 512       // 4*DIM LSTM gates
#define NROUNDS 26

// adjacency list segmentation (deterministic build, no atomics)
#define CSEG 16          // segments per clause over NL
#define CSEGLEN 256      // NL/CSEG
#define CSEGCAP 16       // mean 0.38 nnz/seg -> 16 is overflow-proof
#define LSEG 32          // segments per literal over NC
#define LSEGLEN 256      // NC/LSEG
#define LSEGCAP 16

__device__ __forceinline__ float sigf(float x){ return 1.0f/(1.0f+expf(-x)); }

// ---- adjacency build -------------------------------------------------------
// clause lists: one thread per (clause, segment), scans 256 literal rows.
// consecutive threads -> consecutive clause columns -> coalesced.
__global__ void k_build_cseg(const float* __restrict__ adj,
                             int* __restrict__ scnt, int* __restrict__ slst){
  int idx = blockIdx.x*blockDim.x + threadIdx.x;   // [0, NC*CSEG)
  int c = idx & (NC-1);
  int s = idx >> 13;           // /NC
  if (s >= CSEG) return;
  int base = s*CSEGLEN;
  int* out = slst + ((size_t)c*CSEG + s)*CSEGCAP;
  int n = 0;
  for (int i = 0; i < CSEGLEN; ++i){
    float v = adj[(size_t)(base+i)*NC + c];
    if (v != 0.0f){ if (n < CSEGCAP) out[n] = base+i; ++n; }
  }
  scnt[c*CSEG+s] = n < CSEGCAP ? n : CSEGCAP;
}

// literal lists: one wave per (literal, segment), ballot-compaction keeps
// deterministic ascending order without atomics. coalesced row reads.
__global__ void k_build_lseg(const float* __restrict__ adj,
                             int* __restrict__ scnt, int* __restrict__ slst){
  int gtid = blockIdx.x*blockDim.x + threadIdx.x;
  int wid  = gtid >> 6;          // wave id over NL*LSEG
  int lane = threadIdx.x & 63;
  int l = wid >> 5;              // /LSEG
  int s = wid & (LSEG-1);
  if (l >= NL) return;
  int base = s*LSEGLEN;
  int* out = slst + ((size_t)l*LSEG + s)*LSEGCAP;
  int n = 0;
  for (int it = 0; it < LSEGLEN/64; ++it){
    int c = base + it*64 + lane;
    float v = adj[(size_t)l*NC + c];
    unsigned long long m = __ballot(v != 0.0f);
    if (v != 0.0f){
      int pos = n + __popcll(m & ((1ull<<lane)-1ull));
      if (pos < LSEGCAP) out[pos] = c;
    }
    n += __popcll(m);
  }
  if (lane == 0) scnt[l*LSEG+s] = n < LSEGCAP ? n : LSEGCAP;
}

// ---- state init ------------------------------------------------------------
__global__ void k_init(const float* __restrict__ liw, const float* __restrict__ lib,
                       const float* __restrict__ ciw, const float* __restrict__ cib,
                       float* __restrict__ Lh, float* __restrict__ Lc,
                       float* __restrict__ Ch, float* __restrict__ Cc){
  int idx = blockIdx.x*blockDim.x + threadIdx.x;
  int d = idx & (DIM-1);
  if (idx < NL*DIM){ Lh[idx] = liw[d] + lib[d]; Lc[idx] = 0.0f; }
  if (idx < NC*DIM){ Ch[idx] = ciw[d] + cib[d]; Cc[idx] = 0.0f; }
}

// ---- fused 3-layer MLP (128->128->128->128), 32-row tile, 256 threads ------
// thread owns 2 output cols x 8 rows; x reads are wave-broadcast LDS b128.
template<bool RELU>
__device__ __forceinline__ void mlp_layer(const float* xs, float* ys,
                                          const float* __restrict__ W,
                                          const float* __restrict__ B, int tid){
  int jj = tid & 63, rg = tid >> 6;
  int j0 = jj*2, j1 = j0+1;
  float acc0[8], acc1[8];
#pragma unroll
  for (int r = 0; r < 8; ++r){ acc0[r]=0.f; acc1[r]=0.f; }
  const float* xbase = xs + (size_t)(rg*8)*DIM;
  for (int k0 = 0; k0 < DIM; k0 += 4){
    float4 w0 = *(const float4*)&W[(size_t)j0*DIM + k0];
    float4 w1 = *(const float4*)&W[(size_t)j1*DIM + k0];
#pragma unroll
    for (int r = 0; r < 8; ++r){
      float4 x = *(const float4*)&xbase[(size_t)r*DIM + k0];
      acc0[r] += x.x*w0.x + x.y*w0.y + x.z*w0.z + x.w*w0.w;
      acc1[r] += x.x*w1.x + x.y*w1.y + x.z*w1.z + x.w*w1.w;
    }
  }
  float b0 = B[j0], b1 = B[j1];
#pragma unroll
  for (int r = 0; r < 8; ++r){
    float v0 = acc0[r]+b0, v1 = acc1[r]+b1;
    if (RELU){ v0 = fmaxf(v0, 0.f); v1 = fmaxf(v1, 0.f); }
    ys[(size_t)(rg*8+r)*DIM + j0] = v0;
    ys[(size_t)(rg*8+r)*DIM + j1] = v1;
  }
}

__global__ void k_mlp3(const float* __restrict__ in, float* __restrict__ out,
                       const float* __restrict__ w1, const float* __restrict__ b1,
                       const float* __restrict__ w2, const float* __restrict__ b2,
                       const float* __restrict__ w3, const float* __restrict__ b3){
  __shared__ __align__(16) float xs[32][DIM];
  __shared__ __align__(16) float ys[32][DIM];
  int r0 = blockIdx.x*32;
  int tid = threadIdx.x;
#pragma unroll
  for (int i = 0; i < 4; ++i){
    int e = tid + i*256;            // float4 index over 32*32
    int row = e >> 5, c4 = e & 31;
    *(float4*)&xs[row][c4*4] = *(const float4*)&in[(size_t)(r0+row)*DIM + c4*4];
  }
  __syncthreads();
  mlp_layer<true >(&xs[0][0], &ys[0][0], w1, b1, tid);
  __syncthreads();
  mlp_layer<true >(&ys[0][0], &xs[0][0], w2, b2, tid);
  __syncthreads();
  mlp_layer<false>(&xs[0][0], &ys[0][0], w3, b3, tid);
  __syncthreads();
#pragma unroll
  for (int i = 0; i < 4; ++i){
    int e = tid + i*256;
    int row = e >> 5, c4 = e & 31;
    *(float4*)&out[(size_t)(r0+row)*DIM + c4*4] = *(const float4*)&ys[row][c4*4];
  }
}

// ---- clause side: gather LC_msg + LSTM update ------------------------------
// 16 clause rows per block, 256 threads. thread computes gates j=tid, tid+256
// for all 16 rows (weight element reused 16x).
__global__ void k_clause_upd(const float* __restrict__ Lpre,
                             const int* __restrict__ scnt, const int* __restrict__ slst,
                             float* __restrict__ Ch, float* __restrict__ Cc,
                             const float* __restrict__ wih, const float* __restrict__ whh,
                             const float* __restrict__ bih, const float* __restrict__ bhh){
  __shared__ __align__(16) float xs[16][DIM];
  __shared__ __align__(16) float hs[16][DIM];
  __shared__ __align__(16) float gs[16][NG];
  int c0 = blockIdx.x*16;
  int tid = threadIdx.x;
#pragma unroll
  for (int i = 0; i < 2; ++i){
    int e = tid + i*256; int row = e >> 5, c4 = e & 31;
    *(float4*)&hs[row][c4*4] = *(const float4*)&Ch[(size_t)(c0+row)*DIM + c4*4];
  }
  int j = tid & 127, rh = tid >> 7;
  for (int rr = 0; rr < 8; ++rr){
    int r = rr*2 + rh;
    int c = c0 + r;
    float s = 0.f;
    for (int sg = 0; sg < CSEG; ++sg){
      int n = scnt[c*CSEG+sg];
      const int* lst = slst + ((size_t)c*CSEG + sg)*CSEGCAP;
      for (int t = 0; t < n; ++t)
        s += Lpre[(size_t)lst[t]*DIM + j];
    }
    xs[r][j] = s;
  }
  __syncthreads();
  float a1[16], a2[16];
#pragma unroll
  for (int r = 0; r < 16; ++r){ a1[r]=0.f; a2[r]=0.f; }
  int j1 = tid, j2 = tid + 256;
  for (int k0 = 0; k0 < DIM; k0 += 4){
    float4 wx1 = *(const float4*)&wih[(size_t)j1*DIM + k0];
    float4 wx2 = *(const float4*)&wih[(size_t)j2*DIM + k0];
    float4 wh1 = *(const float4*)&whh[(size_t)j1*DIM + k0];
    float4 wh2 = *(const float4*)&whh[(size_t)j2*DIM + k0];
#pragma unroll
    for (int r = 0; r < 16; ++r){
      float4 x = *(const float4*)&xs[r][k0];
      float4 h = *(const float4*)&hs[r][k0];
      a1[r] += x.x*wx1.x + x.y*wx1.y + x.z*wx1.z + x.w*wx1.w
             + h.x*wh1.x + h.y*wh1.y + h.z*wh1.z + h.w*wh1.w;
      a2[r] += x.x*wx2.x + x.y*wx2.y + x.z*wx2.z + x.w*wx2.w
             + h.x*wh2.x + h.y*wh2.y + h.z*wh2.z + h.w*wh2.w;
    }
  }
  float bb1 = bih[j1]+bhh[j1], bb2 = bih[j2]+bhh[j2];
#pragma unroll
  for (int r = 0; r < 16; ++r){ gs[r][j1] = a1[r]+bb1; gs[r][j2] = a2[r]+bb2; }
  __syncthreads();
#pragma unroll
  for (int i = 0; i < 8; ++i){
    int e = tid + i*256; int r = e >> 7, d = e & 127;
    float ig = gs[r][d], fg = gs[r][DIM+d], gg = gs[r][2*DIM+d], og = gs[r][3*DIM+d];
    size_t off = (size_t)(c0+r)*DIM + d;
    float cn = sigf(fg)*Cc[off] + sigf(ig)*tanhf(gg);
    float hn = sigf(og)*tanhf(cn);
    Cc[off] = cn;
    Ch[off] = hn;
  }
}

// ---- literal side: gather CL_msg, concat flip, LSTM update -----------------
__global__ void k_lit_upd(const float* __restrict__ Cpre,
                          const int* __restrict__ scnt, const int* __restrict__ slst,
                          const float* __restrict__ Lh_old, float* __restrict__ Lh_new,
                          float* __restrict__ Lc,
                          const float* __restrict__ wih, const float* __restrict__ whh,
                          const float* __restrict__ bih, const float* __restrict__ bhh){
  __shared__ __align__(16) float xs[16][2*DIM];   // [CL_msg | L_flip]
  __shared__ __align__(16) float hs[16][DIM];
  __shared__ __align__(16) float gs[16][NG];
  int l0 = blockIdx.x*16;
  int tid = threadIdx.x;
#pragma unroll
  for (int i = 0; i < 2; ++i){
    int e = tid + i*256; int row = e >> 5, c4 = e & 31;
    *(float4*)&hs[row][c4*4] = *(const float4*)&Lh_old[(size_t)(l0+row)*DIM + c4*4];
    int fl = (l0 + row + NV) & (NL-1);
    *(float4*)&xs[row][DIM + c4*4] = *(const float4*)&Lh_old[(size_t)fl*DIM + c4*4];
  }
  int j = tid & 127, rh = tid >> 7;
  for (int rr = 0; rr < 8; ++rr){
    int r = rr*2 + rh;
    int l = l0 + r;
    float s = 0.f;
    for (int sg = 0; sg < LSEG; ++sg){
      int n = scnt[l*LSEG+sg];
      const int* lst = slst + ((size_t)l*LSEG + sg)*LSEGCAP;
      for (int t = 0; t < n; ++t)
        s += Cpre[(size_t)lst[t]*DIM + j];
    }
    xs[r][j] = s;
  }
  __syncthreads();
  float a1[16], a2[16];
#pragma unroll
  for (int r = 0; r < 16; ++r){ a1[r]=0.f; a2[r]=0.f; }
  int j1 = tid, j2 = tid + 256;
  for (int k0 = 0; k0 < 2*DIM; k0 += 4){
    float4 wx1 = *(const float4*)&wih[(size_t)j1*(2*DIM) + k0];
    float4 wx2 = *(const float4*)&wih[(size_t)j2*(2*DIM) + k0];
#pragma unroll
    for (int r = 0; r < 16; ++r){
      float4 x = *(const float4*)&xs[r][k0];
      a1[r] += x.x*wx1.x + x.y*wx1.y + x.z*wx1.z + x.w*wx1.w;
      a2[r] += x.x*wx2.x + x.y*wx2.y + x.z*wx2.z + x.w*wx2.w;
    }
  }
  for (int k0 = 0; k0 < DIM; k0 += 4){
    float4 wh1 = *(const float4*)&whh[(size_t)j1*DIM + k0];
    float4 wh2 = *(const float4*)&whh[(size_t)j2*DIM + k0];
#pragma unroll
    for (int r = 0; r < 16; ++r){
      float4 h = *(const float4*)&hs[r][k0];
      a1[r] += h.x*wh1.x + h.y*wh1.y + h.z*wh1.z + h.w*wh1.w;
      a2[r] += h.x*wh2.x + h.y*wh2.y + h.z*wh2.z + h.w*wh2.w;
    }
  }
  float bb1 = bih[j1]+bhh[j1], bb2 = bih[j2]+bhh[j2];
#pragma unroll
  for (int r = 0; r < 16; ++r){ gs[r][j1] = a1[r]+bb1; gs[r][j2] = a2[r]+bb2; }
  __syncthreads();
#pragma unroll
  for (int i = 0; i < 8; ++i){
    int e = tid + i*256; int r = e >> 7, d = e & 127;
    float ig = gs[r][d], fg = gs[r][DIM+d], gg = gs[r][2*DIM+d], og = gs[r][3*DIM+d];
    size_t off = (size_t)(l0+r)*DIM + d;
    float cn = sigf(fg)*Lc[off] + sigf(ig)*tanhf(gg);
    float hn = sigf(og)*tanhf(cn);
    Lc[off] = cn;
    Lh_new[off] = hn;
  }
}

// ---- vote MLP (128->128->128->1), writes vote[] and d_out[1..NL] -----------
__global__ void k_vote(const float* __restrict__ Lh, float* __restrict__ vote,
                       float* __restrict__ dout,
                       const float* __restrict__ w1, const float* __restrict__ b1,
                       const float* __restrict__ w2, const float* __restrict__ b2,
                       const float* __restrict__ w3, const float* __restrict__ b3){
  __shared__ __align__(16) float xs[32][DIM];
  __shared__ __align__(16) float ys[32][DIM];
  __shared__ float ps[32][8];
  int r0 = blockIdx.x*32;
  int tid = threadIdx.x;
#pragma unroll
  for (int i = 0; i < 4; ++i){
    int e = tid + i*256; int row = e >> 5, c4 = e & 31;
    *(float4*)&xs[row][c4*4] = *(const float4*)&Lh[(size_t)(r0+row)*DIM + c4*4];
  }
  __syncthreads();
  mlp_layer<true>(&xs[0][0], &ys[0][0], w1, b1, tid);
  __syncthreads();
  mlp_layer<true>(&ys[0][0], &xs[0][0], w2, b2, tid);
  __syncthreads();
  int r = tid >> 3, q = tid & 7;
  float s = 0.f;
  for (int k = q*16; k < q*16+16; ++k) s += xs[r][k]*w3[k];
  ps[r][q] = s;
  __syncthreads();
  if (tid < 32){
    float t = b3[0];
#pragma unroll
    for (int qq = 0; qq < 8; ++qq) t += ps[tid][qq];
    vote[r0+tid] = t;
    dout[1 + r0 + tid] = t;
  }
}

__global__ void k_copy_logits(const float* __restrict__ Lh, float* __restrict__ dout){
  int idx = blockIdx.x*blockDim.x + threadIdx.x;
  if (idx < NL*DIM) dout[1 + NL + idx] = Lh[idx];
}

__global__ void k_mean(const float* __restrict__ vote, float* __restrict__ dout){
  __shared__ float red[256];
  int tid = threadIdx.x;
  float s = 0.f;
  for (int i = tid; i < NL; i += 256) s += vote[i];
  red[tid] = s;
  __syncthreads();
  for (int w = 128; w > 0; w >>= 1){
    if (tid < w) red[tid] += red[tid+w];
    __syncthreads();
  }
  if (tid == 0) dout[0] = red[0] / (float)NL;
}

// ---- host ------------------------------------------------------------------
extern "C" void kernel_launch(void* const* d_in, const int* in_sizes, int n_in,
                              void* d_out, int out_size, void* d_ws, size_t ws_size,
                              hipStream_t stream){
  const float* adj      = (const float*)d_in[0];
  const float* l_init_w = (const float*)d_in[1];
  const float* l_init_b = (const float*)d_in[2];
  const float* c_init_w = (const float*)d_in[3];
  const float* c_init_b = (const float*)d_in[4];
  const float* lmsg_w1  = (const float*)d_in[5];
  const float* lmsg_b1  = (const float*)d_in[6];
  const float* lmsg_w2  = (const float*)d_in[7];
  const float* lmsg_b2  = (const float*)d_in[8];
  const float* lmsg_w3  = (const float*)d_in[9];
  const float* lmsg_b3  = (const float*)d_in[10];
  const float* cmsg_w1  = (const float*)d_in[11];
  const float* cmsg_b1  = (const float*)d_in[12];
  const float* cmsg_w2  = (const float*)d_in[13];
  const float* cmsg_b2  = (const float*)d_in[14];
  const float* cmsg_w3  = (const float*)d_in[15];
  const float* cmsg_b3  = (const float*)d_in[16];
  const float* l_wih    = (const float*)d_in[17];
  const float* l_whh    = (const float*)d_in[18];
  const float* l_bih    = (const float*)d_in[19];
  const float* l_bhh    = (const float*)d_in[20];
  const float* c_wih    = (const float*)d_in[21];
  const float* c_whh    = (const float*)d_in[22];
  const float* c_bih    = (const float*)d_in[23];
  const float* c_bhh    = (const float*)d_in[24];
  const float* lvote_w1 = (const float*)d_in[25];
  const float* lvote_b1 = (const float*)d_in[26];
  const float* lvote_w2 = (const float*)d_in[27];
  const float* lvote_b2 = (const float*)d_in[28];
  const float* lvote_w3 = (const float*)d_in[29];
  const float* lvote_b3 = (const float*)d_in[30];

  char* p = (char*)d_ws;
  auto alloc = [&](size_t bytes) -> void* {
    void* r = (void*)p;
    p += (bytes + 255) & ~(size_t)255;
    return r;
  };
  float* LhA   = (float*)alloc((size_t)NL*DIM*4);
  float* LhB   = (float*)alloc((size_t)NL*DIM*4);
  float* Lc    = (float*)alloc((size_t)NL*DIM*4);
  float* Ch    = (float*)alloc((size_t)NC*DIM*4);
  float* Cc    = (float*)alloc((size_t)NC*DIM*4);
  float* Lpre  = (float*)alloc((size_t)NL*DIM*4);
  float* Cpre  = (float*)alloc((size_t)NC*DIM*4);
  float* vote  = (float*)alloc((size_t)NL*4);
  int* scnt_c  = (int*)alloc((size_t)NC*CSEG*4);
  int* slst_c  = (int*)alloc((size_t)NC*CSEG*CSEGCAP*4);
  int* scnt_l  = (int*)alloc((size_t)NL*LSEG*4);
  int* slst_l  = (int*)alloc((size_t)NL*LSEG*LSEGCAP*4);
  (void)ws_size; (void)in_sizes; (void)n_in; (void)out_size;

  k_build_cseg<<<NC*CSEG/256, 256, 0, stream>>>(adj, scnt_c, slst_c);
  k_build_lseg<<<NL*LSEG*64/256, 256, 0, stream>>>(adj, scnt_l, slst_l);
  k_init<<<NC*DIM/256, 256, 0, stream>>>(l_init_w, l_init_b, c_init_w, c_init_b,
                                         LhA, Lc, Ch, Cc);

  float* Lh_cur = LhA;
  float* Lh_nxt = LhB;
  for (int r = 0; r < NROUNDS; ++r){
    k_mlp3<<<NL/32, 256, 0, stream>>>(Lh_cur, Lpre,
                                      lmsg_w1, lmsg_b1, lmsg_w2, lmsg_b2, lmsg_w3, lmsg_b3);
    k_clause_upd<<<NC/16, 256, 0, stream>>>(Lpre, scnt_c, slst_c, Ch, Cc,
                                            c_wih, c_whh, c_bih, c_bhh);
    k_mlp3<<<NC/32, 256, 0, stream>>>(Ch, Cpre,
                                      cmsg_w1, cmsg_b1, cmsg_w2, cmsg_b2, cmsg_w3, cmsg_b3);
    k_lit_upd<<<NL/16, 256, 0, stream>>>(Cpre, scnt_l, slst_l, Lh_cur, Lh_nxt, Lc,
                                         l_wih, l_whh, l_bih, l_bhh);
    float* t = Lh_cur; Lh_cur = Lh_nxt; Lh_nxt = t;
  }

  k_vote<<<NL/32, 256, 0, stream>>>(Lh_cur, vote, (float*)d_out,
                                    lvote_w1, lvote_b1, lvote_w2, lvote_b2,
                                    lvote_w3, lvote_b3);
  k_copy_logits<<<(NL*DIM)/256, 256, 0, stream>>>(Lh_cur, (float*)d_out);
  k_mean<<<1, 256, 0, stream>>>(vote, (float*)d_out);
}

// Round 2
// 7719.115 us; speedup vs baseline: 1.0433x; 1.0433x over previous
//
#include <hip/hip_runtime.h>
#include <math.h>

#define NL 4096      // 2*N_VARS literals
#define NV 2048      // N_VARS
#define NC 8192      // N_CLAUSES
#define DIM 128
#define NG 512       // 4*DIM LSTM gates
#define NROUNDS 26

// segmented build (deterministic, no atomics), then merged to compact lists
#define CSEG 16
#define CSEGLEN 256      // NL/CSEG
#define CSEGCAP 16
#define LSEG 32
#define LSEGLEN 256      // NC/LSEG
#define LSEGCAP 16
#define CCAP 32          // Poisson(6.1): P(>32) ~ 1e-16
#define LCAP 48          // Poisson(12.3): P(>48) ~ 1e-15

__device__ __forceinline__ float sigf(float x){ return 1.0f/(1.0f+expf(-x)); }

// ---- adjacency build -------------------------------------------------------
__global__ void k_build_cseg(const float* __restrict__ adj,
                             int* __restrict__ scnt, int* __restrict__ slst){
  int idx = blockIdx.x*blockDim.x + threadIdx.x;   // [0, NC*CSEG)
  int c = idx & (NC-1);
  int s = idx >> 13;
  if (s >= CSEG) return;
  int base = s*CSEGLEN;
  int* out = slst + ((size_t)c*CSEG + s)*CSEGCAP;
  int n = 0;
  for (int i = 0; i < CSEGLEN; ++i){
    float v = adj[(size_t)(base+i)*NC + c];
    if (v != 0.0f){ if (n < CSEGCAP) out[n] = base+i; ++n; }
  }
  scnt[c*CSEG+s] = n < CSEGCAP ? n : CSEGCAP;
}

__global__ void k_build_lseg(const float* __restrict__ adj,
                             int* __restrict__ scnt, int* __restrict__ slst){
  int gtid = blockIdx.x*blockDim.x + threadIdx.x;
  int wid  = gtid >> 6;
  int lane = threadIdx.x & 63;
  int l = wid >> 5;
  int s = wid & (LSEG-1);
  if (l >= NL) return;
  int base = s*LSEGLEN;
  int* out = slst + ((size_t)l*LSEG + s)*LSEGCAP;
  int n = 0;
  for (int it = 0; it < LSEGLEN/64; ++it){
    int c = base + it*64 + lane;
    float v = adj[(size_t)l*NC + c];
    unsigned long long m = __ballot(v != 0.0f);
    if (v != 0.0f){
      int pos = n + __popcll(m & ((1ull<<lane)-1ull));
      if (pos < LSEGCAP) out[pos] = c;
    }
    n += __popcll(m);
  }
  if (lane == 0) scnt[l*LSEG+s] = n < LSEGCAP ? n : LSEGCAP;
}

__global__ void k_merge_c(const int* __restrict__ scnt, const int* __restrict__ slst,
                          int* __restrict__ cnt, int* __restrict__ lst){
  int c = blockIdx.x*blockDim.x + threadIdx.x;
  if (c >= NC) return;
  int n = 0;
  for (int s = 0; s < CSEG; ++s){
    int m = scnt[c*CSEG+s];
    const int* in = slst + ((size_t)c*CSEG+s)*CSEGCAP;
    for (int t = 0; t < m; ++t){ if (n < CCAP) lst[(size_t)c*CCAP+n] = in[t]; ++n; }
  }
  cnt[c] = n < CCAP ? n : CCAP;
}

__global__ void k_merge_l(const int* __restrict__ scnt, const int* __restrict__ slst,
                          int* __restrict__ cnt, int* __restrict__ lst){
  int l = blockIdx.x*blockDim.x + threadIdx.x;
  if (l >= NL) return;
  int n = 0;
  for (int s = 0; s < LSEG; ++s){
    int m = scnt[l*LSEG+s];
    const int* in = slst + ((size_t)l*LSEG+s)*LSEGCAP;
    for (int t = 0; t < m; ++t){ if (n < LCAP) lst[(size_t)l*LCAP+n] = in[t]; ++n; }
  }
  cnt[l] = n < LCAP ? n : LCAP;
}

// ---- state init ------------------------------------------------------------
__global__ void k_init(const float* __restrict__ liw, const float* __restrict__ lib,
                       const float* __restrict__ ciw, const float* __restrict__ cib,
                       float* __restrict__ Lh, float* __restrict__ Lc,
                       float* __restrict__ Ch, float* __restrict__ Cc){
  int idx = blockIdx.x*blockDim.x + threadIdx.x;
  int d = idx & (DIM-1);
  if (idx < NL*DIM){ Lh[idx] = liw[d] + lib[d]; Lc[idx] = 0.0f; }
  if (idx < NC*DIM){ Ch[idx] = ciw[d] + cib[d]; Cc[idx] = 0.0f; }
}

// ---- fused 3-layer MLP, 8-row tile, 512 threads ----------------------------
// thread: col j = tid&127, rows 2*(tid>>7), 2*(tid>>7)+1.
// x reads are same-address LDS broadcasts within a wave (conflict-free).
template<bool RELU>
__device__ __forceinline__ void mlp_layer8(const float (*__restrict__ xs)[DIM],
                                           float (*__restrict__ ys)[DIM],
                                           const float* __restrict__ W,
                                           const float* __restrict__ B, int tid){
  int j = tid & 127, rg = tid >> 7;
  int r0 = rg*2, r1 = r0+1;
  float a0 = 0.f, a1 = 0.f;
  for (int k0 = 0; k0 < DIM; k0 += 4){
    float4 w  = *(const float4*)&W[(size_t)j*DIM + k0];
    float4 x0 = *(const float4*)&xs[r0][k0];
    float4 x1 = *(const float4*)&xs[r1][k0];
    a0 += x0.x*w.x + x0.y*w.y + x0.z*w.z + x0.w*w.w;
    a1 += x1.x*w.x + x1.y*w.y + x1.z*w.z + x1.w*w.w;
  }
  float b = B[j];
  float v0 = a0+b, v1 = a1+b;
  if (RELU){ v0 = fmaxf(v0, 0.f); v1 = fmaxf(v1, 0.f); }
  ys[r0][j] = v0;
  ys[r1][j] = v1;
}

__global__ __launch_bounds__(512, 8)
void k_mlp3(const float* __restrict__ in, float* __restrict__ out,
            const float* __restrict__ w1, const float* __restrict__ b1,
            const float* __restrict__ w2, const float* __restrict__ b2,
            const float* __restrict__ w3, const float* __restrict__ b3){
  __shared__ __align__(16) float xs[8][DIM];
  __shared__ __align__(16) float ys[8][DIM];
  int r0 = blockIdx.x*8;
  int tid = threadIdx.x;
  if (tid < 256){
    int row = tid >> 5, c4 = tid & 31;
    *(float4*)&xs[row][c4*4] = *(const float4*)&in[(size_t)(r0+row)*DIM + c4*4];
  }
  __syncthreads();
  mlp_layer8<true >(xs, ys, w1, b1, tid);
  __syncthreads();
  mlp_layer8<true >(ys, xs, w2, b2, tid);
  __syncthreads();
  mlp_layer8<false>(xs, ys, w3, b3, tid);
  __syncthreads();
  if (tid < 256){
    int row = tid >> 5, c4 = tid & 31;
    *(float4*)&out[(size_t)(r0+row)*DIM + c4*4] = *(const float4*)&ys[row][c4*4];
  }
}

// ---- clause side: gather LC_msg + LSTM update ------------------------------
// 8 clauses/block, 512 threads. thread = one gate col x 8 rows.
__global__ __launch_bounds__(512, 8)
void k_clause_upd(const float* __restrict__ Lpre,
                  const int* __restrict__ cnt, const int* __restrict__ lst,
                  float* __restrict__ Ch, float* __restrict__ Cc,
                  const float* __restrict__ wih, const float* __restrict__ whh,
                  const float* __restrict__ bih, const float* __restrict__ bhh){
  __shared__ __align__(16) float xs[8][DIM];
  __shared__ __align__(16) float hs[8][DIM];
  __shared__ __align__(16) float gs[8][NG];
  int c0 = blockIdx.x*8;
  int tid = threadIdx.x;
  if (tid < 256){
    int row = tid >> 5, c4 = tid & 31;
    *(float4*)&hs[row][c4*4] = *(const float4*)&Ch[(size_t)(c0+row)*DIM + c4*4];
  }
  int j = tid & 127, rslot = tid >> 7;     // 4 row slots x 2 rows
#pragma unroll
  for (int rr = 0; rr < 2; ++rr){
    int r = rslot + rr*4;
    int c = c0 + r;
    float s = 0.f;
    int n = cnt[c];
    const int* ls = lst + (size_t)c*CCAP;
    for (int t = 0; t < n; ++t) s += Lpre[(size_t)ls[t]*DIM + j];
    xs[r][j] = s;
  }
  __syncthreads();
  float acc[8];
#pragma unroll
  for (int r = 0; r < 8; ++r) acc[r] = 0.f;
  int jg = tid;                            // gate col 0..511
  for (int k0 = 0; k0 < DIM; k0 += 4){
    float4 w = *(const float4*)&wih[(size_t)jg*DIM + k0];
#pragma unroll
    for (int r = 0; r < 8; ++r){
      float4 x = *(const float4*)&xs[r][k0];
      acc[r] += x.x*w.x + x.y*w.y + x.z*w.z + x.w*w.w;
    }
  }
  for (int k0 = 0; k0 < DIM; k0 += 4){
    float4 w = *(const float4*)&whh[(size_t)jg*DIM + k0];
#pragma unroll
    for (int r = 0; r < 8; ++r){
      float4 h = *(const float4*)&hs[r][k0];
      acc[r] += h.x*w.x + h.y*w.y + h.z*w.z + h.w*w.w;
    }
  }
  float bb = bih[jg] + bhh[jg];
#pragma unroll
  for (int r = 0; r < 8; ++r) gs[r][jg] = acc[r] + bb;
  __syncthreads();
#pragma unroll
  for (int i = 0; i < 2; ++i){
    int e = tid + i*512; int r = e >> 7, d = e & 127;
    float ig = gs[r][d], fg = gs[r][DIM+d], gg = gs[r][2*DIM+d], og = gs[r][3*DIM+d];
    size_t off = (size_t)(c0+r)*DIM + d;
    float cn = sigf(fg)*Cc[off] + sigf(ig)*tanhf(gg);
    float hn = sigf(og)*tanhf(cn);
    Cc[off] = cn;
    Ch[off] = hn;
  }
}

// ---- literal side: gather CL_msg, concat flip, LSTM update -----------------
__global__ __launch_bounds__(512, 8)
void k_lit_upd(const float* __restrict__ Cpre,
               const int* __restrict__ cnt, const int* __restrict__ lst,
               const float* __restrict__ Lh_old, float* __restrict__ Lh_new,
               float* __restrict__ Lc,
               const float* __restrict__ wih, const float* __restrict__ whh,
               const float* __restrict__ bih, const float* __restrict__ bhh){
  __shared__ __align__(16) float xs[8][2*DIM];   // [CL_msg | L_flip]
  __shared__ __align__(16) float hs[8][DIM];
  __shared__ __align__(16) float gs[8][NG];
  int l0 = blockIdx.x*8;
  int tid = threadIdx.x;
  {
    int row = (tid & 255) >> 5, c4 = tid & 31;
    if (tid < 256){
      *(float4*)&hs[row][c4*4] = *(const float4*)&Lh_old[(size_t)(l0+row)*DIM + c4*4];
    } else {
      int fl = (l0 + row + NV) & (NL-1);
      *(float4*)&xs[row][DIM + c4*4] = *(const float4*)&Lh_old[(size_t)fl*DIM + c4*4];
    }
  }
  int j = tid & 127, rslot = tid >> 7;
#pragma unroll
  for (int rr = 0; rr < 2; ++rr){
    int r = rslot + rr*4;
    int l = l0 + r;
    float s = 0.f;
    int n = cnt[l];
    const int* ls = lst + (size_t)l*LCAP;
    for (int t = 0; t < n; ++t) s += Cpre[(size_t)ls[t]*DIM + j];
    xs[r][j] = s;
  }
  __syncthreads();
  float acc[8];
#pragma unroll
  for (int r = 0; r < 8; ++r) acc[r] = 0.f;
  int jg = tid;
  for (int k0 = 0; k0 < 2*DIM; k0 += 4){
    float4 w = *(const float4*)&wih[(size_t)jg*(2*DIM) + k0];
#pragma unroll
    for (int r = 0; r < 8; ++r){
      float4 x = *(const float4*)&xs[r][k0];
      acc[r] += x.x*w.x + x.y*w.y + x.z*w.z + x.w*w.w;
    }
  }
  for (int k0 = 0; k0 < DIM; k0 += 4){
    float4 w = *(const float4*)&whh[(size_t)jg*DIM + k0];
#pragma unroll
    for (int r = 0; r < 8; ++r){
      float4 h = *(const float4*)&hs[r][k0];
      acc[r] += h.x*w.x + h.y*w.y + h.z*w.z + h.w*w.w;
    }
  }
  float bb = bih[jg] + bhh[jg];
#pragma unroll
  for (int r = 0; r < 8; ++r) gs[r][jg] = acc[r] + bb;
  __syncthreads();
#pragma unroll
  for (int i = 0; i < 2; ++i){
    int e = tid + i*512; int r = e >> 7, d = e & 127;
    float ig = gs[r][d], fg = gs[r][DIM+d], gg = gs[r][2*DIM+d], og = gs[r][3*DIM+d];
    size_t off = (size_t)(l0+r)*DIM + d;
    float cn = sigf(fg)*Lc[off] + sigf(ig)*tanhf(gg);
    float hn = sigf(og)*tanhf(cn);
    Lc[off] = cn;
    Lh_new[off] = hn;
  }
}

// ---- vote MLP (128->128->128->1) -------------------------------------------
template<bool RELU>
__device__ __forceinline__ void mlp_layer32(const float* xs, float* ys,
                                            const float* __restrict__ W,
                                            const float* __restrict__ B, int tid){
  int jj = tid & 63, rg = tid >> 6;
  int j0 = jj*2, j1 = j0+1;
  float acc0[8], acc1[8];
#pragma unroll
  for (int r = 0; r < 8; ++r){ acc0[r]=0.f; acc1[r]=0.f; }
  const float* xbase = xs + (size_t)(rg*8)*DIM;
  for (int k0 = 0; k0 < DIM; k0 += 4){
    float4 w0 = *(const float4*)&W[(size_t)j0*DIM + k0];
    float4 w1 = *(const float4*)&W[(size_t)j1*DIM + k0];
#pragma unroll
    for (int r = 0; r < 8; ++r){
      float4 x = *(const float4*)&xbase[(size_t)r*DIM + k0];
      acc0[r] += x.x*w0.x + x.y*w0.y + x.z*w0.z + x.w*w0.w;
      acc1[r] += x.x*w1.x + x.y*w1.y + x.z*w1.z + x.w*w1.w;
    }
  }
  float b0 = B[j0], b1 = B[j1];
#pragma unroll
  for (int r = 0; r < 8; ++r){
    float v0 = acc0[r]+b0, v1 = acc1[r]+b1;
    if (RELU){ v0 = fmaxf(v0, 0.f); v1 = fmaxf(v1, 0.f); }
    ys[(size_t)(rg*8+r)*DIM + j0] = v0;
    ys[(size_t)(rg*8+r)*DIM + j1] = v1;
  }
}

__global__ void k_vote(const float* __restrict__ Lh, float* __restrict__ vote,
                       float* __restrict__ dout,
                       const float* __restrict__ w1, const float* __restrict__ b1,
                       const float* __restrict__ w2, const float* __restrict__ b2,
                       const float* __restrict__ w3, const float* __restrict__ b3){
  __shared__ __align__(16) float xs[32][DIM];
  __shared__ __align__(16) float ys[32][DIM];
  __shared__ float ps[32][8];
  int r0 = blockIdx.x*32;
  int tid = threadIdx.x;
#pragma unroll
  for (int i = 0; i < 4; ++i){
    int e = tid + i*256; int row = e >> 5, c4 = e & 31;
    *(float4*)&xs[row][c4*4] = *(const float4*)&Lh[(size_t)(r0+row)*DIM + c4*4];
  }
  __syncthreads();
  mlp_layer32<true>(&xs[0][0], &ys[0][0], w1, b1, tid);
  __syncthreads();
  mlp_layer32<true>(&ys[0][0], &xs[0][0], w2, b2, tid);
  __syncthreads();
  int r = tid >> 3, q = tid & 7;
  float s = 0.f;
  for (int k = q*16; k < q*16+16; ++k) s += xs[r][k]*w3[k];
  ps[r][q] = s;
  __syncthreads();
  if (tid < 32){
    float t = b3[0];
#pragma unroll
    for (int qq = 0; qq < 8; ++qq) t += ps[tid][qq];
    vote[r0+tid] = t;
    dout[1 + r0 + tid] = t;
  }
}

__global__ void k_copy_logits(const float* __restrict__ Lh, float* __restrict__ dout){
  int idx = blockIdx.x*blockDim.x + threadIdx.x;
  if (idx < NL*DIM) dout[1 + NL + idx] = Lh[idx];
}

__global__ void k_mean(const float* __restrict__ vote, float* __restrict__ dout){
  __shared__ float red[256];
  int tid = threadIdx.x;
  float s = 0.f;
  for (int i = tid; i < NL; i += 256) s += vote[i];
  red[tid] = s;
  __syncthreads();
  for (int w = 128; w > 0; w >>= 1){
    if (tid < w) red[tid] += red[tid+w];
    __syncthreads();
  }
  if (tid == 0) dout[0] = red[0] / (float)NL;
}

// ---- host ------------------------------------------------------------------
extern "C" void kernel_launch(void* const* d_in, const int* in_sizes, int n_in,
                              void* d_out, int out_size, void* d_ws, size_t ws_size,
                              hipStream_t stream){
  const float* adj      = (const float*)d_in[0];
  const float* l_init_w = (const float*)d_in[1];
  const float* l_init_b = (const float*)d_in[2];
  const float* c_init_w = (const float*)d_in[3];
  const float* c_init_b = (const float*)d_in[4];
  const float* lmsg_w1  = (const float*)d_in[5];
  const float* lmsg_b1  = (const float*)d_in[6];
  const float* lmsg_w2  = (const float*)d_in[7];
  const float* lmsg_b2  = (const float*)d_in[8];
  const float* lmsg_w3  = (const float*)d_in[9];
  const float* lmsg_b3  = (const float*)d_in[10];
  const float* cmsg_w1  = (const float*)d_in[11];
  const float* cmsg_b1  = (const float*)d_in[12];
  const float* cmsg_w2  = (const float*)d_in[13];
  const float* cmsg_b2  = (const float*)d_in[14];
  const float* cmsg_w3  = (const float*)d_in[15];
  const float* cmsg_b3  = (const float*)d_in[16];
  const float* l_wih    = (const float*)d_in[17];
  const float* l_whh    = (const float*)d_in[18];
  const float* l_bih    = (const float*)d_in[19];
  const float* l_bhh    = (const float*)d_in[20];
  const float* c_wih    = (const float*)d_in[21];
  const float* c_whh    = (const float*)d_in[22];
  const float* c_bih    = (const float*)d_in[23];
  const float* c_bhh    = (const float*)d_in[24];
  const float* lvote_w1 = (const float*)d_in[25];
  const float* lvote_b1 = (const float*)d_in[26];
  const float* lvote_w2 = (const float*)d_in[27];
  const float* lvote_b2 = (const float*)d_in[28];
  const float* lvote_w3 = (const float*)d_in[29];
  const float* lvote_b3 = (const float*)d_in[30];

  char* p = (char*)d_ws;
  auto alloc = [&](size_t bytes) -> void* {
    void* r = (void*)p;
    p += (bytes + 255) & ~(size_t)255;
    return r;
  };
  float* LhA   = (float*)alloc((size_t)NL*DIM*4);
  float* LhB   = (float*)alloc((size_t)NL*DIM*4);
  float* Lc    = (float*)alloc((size_t)NL*DIM*4);
  float* Ch    = (float*)alloc((size_t)NC*DIM*4);
  float* Cc    = (float*)alloc((size_t)NC*DIM*4);
  float* Lpre  = (float*)alloc((size_t)NL*DIM*4);
  float* Cpre  = (float*)alloc((size_t)NC*DIM*4);
  float* vote  = (float*)alloc((size_t)NL*4);
  int* scnt_c  = (int*)alloc((size_t)NC*CSEG*4);
  int* slst_c  = (int*)alloc((size_t)NC*CSEG*CSEGCAP*4);
  int* scnt_l  = (int*)alloc((size_t)NL*LSEG*4);
  int* slst_l  = (int*)alloc((size_t)NL*LSEG*LSEGCAP*4);
  int* ccnt    = (int*)alloc((size_t)NC*4);
  int* clst    = (int*)alloc((size_t)NC*CCAP*4);
  int* lcnt    = (int*)alloc((size_t)NL*4);
  int* llst    = (int*)alloc((size_t)NL*LCAP*4);
  (void)ws_size; (void)in_sizes; (void)n_in; (void)out_size;

  k_build_cseg<<<NC*CSEG/256, 256, 0, stream>>>(adj, scnt_c, slst_c);
  k_build_lseg<<<NL*LSEG*64/256, 256, 0, stream>>>(adj, scnt_l, slst_l);
  k_merge_c<<<NC/256, 256, 0, stream>>>(scnt_c, slst_c, ccnt, clst);
  k_merge_l<<<NL/256, 256, 0, stream>>>(scnt_l, slst_l, lcnt, llst);
  k_init<<<NC*DIM/256, 256, 0, stream>>>(l_init_w, l_init_b, c_init_w, c_init_b,
                                         LhA, Lc, Ch, Cc);

  float* Lh_cur = LhA;
  float* Lh_nxt = LhB;
  for (int r = 0; r < NROUNDS; ++r){
    k_mlp3<<<NL/8, 512, 0, stream>>>(Lh_cur, Lpre,
                                     lmsg_w1, lmsg_b1, lmsg_w2, lmsg_b2, lmsg_w3, lmsg_b3);
    k_clause_upd<<<NC/8, 512, 0, stream>>>(Lpre, ccnt, clst, Ch, Cc,
                                           c_wih, c_whh, c_bih, c_bhh);
    k_mlp3<<<NC/8, 512, 0, stream>>>(Ch, Cpre,
                                     cmsg_w1, cmsg_b1, cmsg_w2, cmsg_b2, cmsg_w3, cmsg_b3);
    k_lit_upd<<<NL/8, 512, 0, stream>>>(Cpre, lcnt, llst, Lh_cur, Lh_nxt, Lc,
                                        l_wih, l_whh, l_bih, l_bhh);
    float* t = Lh_cur; Lh_cur = Lh_nxt; Lh_nxt = t;
  }

  k_vote<<<NL/32, 256, 0, stream>>>(Lh_cur, vote, (float*)d_out,
                                    lvote_w1, lvote_b1, lvote_w2, lvote_b2,
                                    lvote_w3, lvote_b3);
  k_copy_logits<<<(NL*DIM)/256, 256, 0, stream>>>(Lh_cur, (float*)d_out);
  k_mean<<<1, 256, 0, stream>>>(vote, (float*)d_out);
}

// Round 3
// 5514.555 us; speedup vs baseline: 1.4603x; 1.3998x over previous
//
#include <hip/hip_runtime.h>
#include <math.h>

#define NL 4096      // 2*N_VARS literals
#define NV 2048      // N_VARS
#define NC 8192      // N_CLAUSES
#define DIM 128
#define NG 512       // 4*DIM LSTM gates
#define NROUNDS 26

// segmented build (deterministic, no atomics), then merged to compact lists
#define CSEG 32
#define CSEGLEN 128      // NL/CSEG
#define CSEGCAP 12
#define LSEG 32
#define LSEGLEN 256      // NC/LSEG
#define LSEGCAP 16
#define CCAP 32          // Poisson(6.1): P(>32) ~ 1e-16
#define LCAP 48          // Poisson(12.3): P(>48) ~ 1e-15

__device__ __forceinline__ float sigf(float x){ return 1.0f/(1.0f+expf(-x)); }

// ---- generic tiled transpose: dst[C][R] = src[R][C]^T ----------------------
__global__ void k_transpose(const float* __restrict__ src, float* __restrict__ dst,
                            int R, int C){
  __shared__ float t[32][33];
  int cb = blockIdx.x*32, rb = blockIdx.y*32;
  int x = threadIdx.x, y = threadIdx.y;
  for (int i = y; i < 32; i += 8){
    int r = rb+i, c = cb+x;
    if (r < R && c < C) t[i][x] = src[(size_t)r*C + c];
  }
  __syncthreads();
  for (int i = y; i < 32; i += 8){
    int c = cb+i, r = rb+x;
    if (c < C && r < R) dst[(size_t)c*R + r] = t[x][i];
  }
}

// ---- adjacency build -------------------------------------------------------
__global__ void k_build_cseg(const float* __restrict__ adj,
                             int* __restrict__ scnt, int* __restrict__ slst){
  int idx = blockIdx.x*blockDim.x + threadIdx.x;   // [0, NC*CSEG)
  int c = idx & (NC-1);
  int s = idx >> 13;
  if (s >= CSEG) return;
  int base = s*CSEGLEN;
  int* out = slst + ((size_t)c*CSEG + s)*CSEGCAP;
  int n = 0;
  for (int i = 0; i < CSEGLEN; ++i){
    float v = adj[(size_t)(base+i)*NC + c];
    if (v != 0.0f){ if (n < CSEGCAP) out[n] = base+i; ++n; }
  }
  scnt[c*CSEG+s] = n < CSEGCAP ? n : CSEGCAP;
}

__global__ void k_build_lseg(const float* __restrict__ adj,
                             int* __restrict__ scnt, int* __restrict__ slst){
  int gtid = blockIdx.x*blockDim.x + threadIdx.x;
  int wid  = gtid >> 6;
  int lane = threadIdx.x & 63;
  int l = wid >> 5;
  int s = wid & (LSEG-1);
  if (l >= NL) return;
  int base = s*LSEGLEN;
  int* out = slst + ((size_t)l*LSEG + s)*LSEGCAP;
  int n = 0;
  for (int it = 0; it < LSEGLEN/64; ++it){
    int c = base + it*64 + lane;
    float v = adj[(size_t)l*NC + c];
    unsigned long long m = __ballot(v != 0.0f);
    if (v != 0.0f){
      int pos = n + __popcll(m & ((1ull<<lane)-1ull));
      if (pos < LSEGCAP) out[pos] = c;
    }
    n += __popcll(m);
  }
  if (lane == 0) scnt[l*LSEG+s] = n < LSEGCAP ? n : LSEGCAP;
}

__global__ void k_merge_c(const int* __restrict__ scnt, const int* __restrict__ slst,
                          int* __restrict__ cnt, int* __restrict__ lst){
  int c = blockIdx.x*blockDim.x + threadIdx.x;
  if (c >= NC) return;
  int n = 0;
  for (int s = 0; s < CSEG; ++s){
    int m = scnt[c*CSEG+s];
    const int* in = slst + ((size_t)c*CSEG+s)*CSEGCAP;
    for (int t = 0; t < m; ++t){ if (n < CCAP) lst[(size_t)c*CCAP+n] = in[t]; ++n; }
  }
  cnt[c] = n < CCAP ? n : CCAP;
}

__global__ void k_merge_l(const int* __restrict__ scnt, const int* __restrict__ slst,
                          int* __restrict__ cnt, int* __restrict__ lst){
  int l = blockIdx.x*blockDim.x + threadIdx.x;
  if (l >= NL) return;
  int n = 0;
  for (int s = 0; s < LSEG; ++s){
    int m = scnt[l*LSEG+s];
    const int* in = slst + ((size_t)l*LSEG+s)*LSEGCAP;
    for (int t = 0; t < m; ++t){ if (n < LCAP) lst[(size_t)l*LCAP+n] = in[t]; ++n; }
  }
  cnt[l] = n < LCAP ? n : LCAP;
}

// ---- state init ------------------------------------------------------------
__global__ void k_init(const float* __restrict__ liw, const float* __restrict__ lib,
                       const float* __restrict__ ciw, const float* __restrict__ cib,
                       float* __restrict__ Lh, float* __restrict__ Lc,
                       float* __restrict__ Ch, float* __restrict__ Cc){
  int idx = blockIdx.x*blockDim.x + threadIdx.x;
  int d = idx & (DIM-1);
  if (idx < NL*DIM){ Lh[idx] = liw[d] + lib[d]; Lc[idx] = 0.0f; }
  if (idx < NC*DIM){ Ch[idx] = ciw[d] + cib[d]; Cc[idx] = 0.0f; }
}

// ---- fused 3-layer MLP, 8 rows/block, 256 threads, k-major weights ---------
// thread: 4 cols (j4 = (tid&31)*4) x 1 row (tid>>5). Weight loads coalesced.
template<bool RELU>
__device__ __forceinline__ void mlp_layer8(const float (*__restrict__ xs)[DIM],
                                           float (*__restrict__ ys)[DIM],
                                           const float* __restrict__ Wt,   // [DIM][DIM] k-major
                                           const float* __restrict__ B, int tid){
  int j4 = (tid & 31)*4, rg = tid >> 5;
  float a0=0.f, a1=0.f, a2=0.f, a3=0.f;
#pragma unroll 4
  for (int k = 0; k < DIM; k += 4){
    float4 w0 = *(const float4*)&Wt[(size_t)(k+0)*DIM + j4];
    float4 w1 = *(const float4*)&Wt[(size_t)(k+1)*DIM + j4];
    float4 w2 = *(const float4*)&Wt[(size_t)(k+2)*DIM + j4];
    float4 w3 = *(const float4*)&Wt[(size_t)(k+3)*DIM + j4];
    float4 x  = *(const float4*)&xs[rg][k];
    a0 += x.x*w0.x + x.y*w1.x + x.z*w2.x + x.w*w3.x;
    a1 += x.x*w0.y + x.y*w1.y + x.z*w2.y + x.w*w3.y;
    a2 += x.x*w0.z + x.y*w1.z + x.z*w2.z + x.w*w3.z;
    a3 += x.x*w0.w + x.y*w1.w + x.z*w2.w + x.w*w3.w;
  }
  float4 b = *(const float4*)&B[j4];
  float4 v = make_float4(a0+b.x, a1+b.y, a2+b.z, a3+b.w);
  if (RELU){
    v.x = fmaxf(v.x,0.f); v.y = fmaxf(v.y,0.f);
    v.z = fmaxf(v.z,0.f); v.w = fmaxf(v.w,0.f);
  }
  *(float4*)&ys[rg][j4] = v;
}

__global__ __launch_bounds__(256, 4)
void k_mlp3(const float* __restrict__ in, float* __restrict__ out,
            const float* __restrict__ w1t, const float* __restrict__ b1,
            const float* __restrict__ w2t, const float* __restrict__ b2,
            const float* __restrict__ w3t, const float* __restrict__ b3){
  __shared__ __align__(16) float xs[8][DIM];
  __shared__ __align__(16) float ys[8][DIM];
  int r0 = blockIdx.x*8;
  int tid = threadIdx.x;
  {
    int row = tid >> 5, c4 = (tid & 31)*4;
    *(float4*)&xs[row][c4] = *(const float4*)&in[(size_t)(r0+row)*DIM + c4];
  }
  __syncthreads();
  mlp_layer8<true >(xs, ys, w1t, b1, tid);
  __syncthreads();
  mlp_layer8<true >(ys, xs, w2t, b2, tid);
  __syncthreads();
  mlp_layer8<false>(xs, ys, w3t, b3, tid);
  __syncthreads();
  {
    int row = tid >> 5, c4 = (tid & 31)*4;
    *(float4*)&out[(size_t)(r0+row)*DIM + c4] = *(const float4*)&ys[row][c4];
  }
}

// ---- clause side: gather + LSTM (one GEMM [8x256]@[256x512]) ---------------
__global__ __launch_bounds__(512, 4)
void k_clause_upd(const float* __restrict__ Lpre,
                  const int* __restrict__ cnt, const int* __restrict__ lst,
                  float* __restrict__ Ch, float* __restrict__ Cc,
                  const float* __restrict__ Wt,    // [256][512] = [wih^T ; whh^T]
                  const float* __restrict__ bih, const float* __restrict__ bhh){
  __shared__ __align__(16) float xs[8][256];   // [LC_msg | h]
  __shared__ __align__(16) float gs[8][NG];
  int c0 = blockIdx.x*8;
  int tid = threadIdx.x;
  if (tid < 256){
    int row = tid >> 5, c4 = (tid & 31)*4;
    *(float4*)&xs[row][DIM + c4] = *(const float4*)&Ch[(size_t)(c0+row)*DIM + c4];
  }
  {
    int j = tid & 127, rslot = tid >> 7;
#pragma unroll
    for (int rr = 0; rr < 2; ++rr){
      int r = rslot*2 + rr;
      int c = c0 + r;
      float s = 0.f;
      int n = cnt[c];
      const int* ls = lst + (size_t)c*CCAP;
      for (int t = 0; t < n; ++t) s += Lpre[(size_t)ls[t]*DIM + j];
      xs[r][j] = s;
    }
  }
  __syncthreads();
  int j4 = (tid & 127)*4, rowg = tid >> 7;
  int ra = rowg*2, rb = ra+1;
  float a0[4] = {0.f,0.f,0.f,0.f}, a1[4] = {0.f,0.f,0.f,0.f};
#pragma unroll 2
  for (int k = 0; k < 256; k += 4){
    float4 w0 = *(const float4*)&Wt[(size_t)(k+0)*NG + j4];
    float4 w1 = *(const float4*)&Wt[(size_t)(k+1)*NG + j4];
    float4 w2 = *(const float4*)&Wt[(size_t)(k+2)*NG + j4];
    float4 w3 = *(const float4*)&Wt[(size_t)(k+3)*NG + j4];
    float4 xa = *(const float4*)&xs[ra][k];
    float4 xb = *(const float4*)&xs[rb][k];
    a0[0] += xa.x*w0.x + xa.y*w1.x + xa.z*w2.x + xa.w*w3.x;
    a0[1] += xa.x*w0.y + xa.y*w1.y + xa.z*w2.y + xa.w*w3.y;
    a0[2] += xa.x*w0.z + xa.y*w1.z + xa.z*w2.z + xa.w*w3.z;
    a0[3] += xa.x*w0.w + xa.y*w1.w + xa.z*w2.w + xa.w*w3.w;
    a1[0] += xb.x*w0.x + xb.y*w1.x + xb.z*w2.x + xb.w*w3.x;
    a1[1] += xb.x*w0.y + xb.y*w1.y + xb.z*w2.y + xb.w*w3.y;
    a1[2] += xb.x*w0.z + xb.y*w1.z + xb.z*w2.z + xb.w*w3.z;
    a1[3] += xb.x*w0.w + xb.y*w1.w + xb.z*w2.w + xb.w*w3.w;
  }
  {
    float4 bi = *(const float4*)&bih[j4];
    float4 bh = *(const float4*)&bhh[j4];
    *(float4*)&gs[ra][j4] = make_float4(a0[0]+bi.x+bh.x, a0[1]+bi.y+bh.y,
                                        a0[2]+bi.z+bh.z, a0[3]+bi.w+bh.w);
    *(float4*)&gs[rb][j4] = make_float4(a1[0]+bi.x+bh.x, a1[1]+bi.y+bh.y,
                                        a1[2]+bi.z+bh.z, a1[3]+bi.w+bh.w);
  }
  __syncthreads();
#pragma unroll
  for (int i = 0; i < 2; ++i){
    int e = tid + i*512; int r = e >> 7, d = e & 127;
    float ig = gs[r][d], fg = gs[r][DIM+d], gg = gs[r][2*DIM+d], og = gs[r][3*DIM+d];
    size_t off = (size_t)(c0+r)*DIM + d;
    float cn = sigf(fg)*Cc[off] + sigf(ig)*tanhf(gg);
    float hn = sigf(og)*tanhf(cn);
    Cc[off] = cn;
    Ch[off] = hn;
  }
}

// ---- literal side: gather + flip + LSTM (GEMM [8x384]@[384x512]) -----------
__global__ __launch_bounds__(512, 4)
void k_lit_upd(const float* __restrict__ Cpre,
               const int* __restrict__ cnt, const int* __restrict__ lst,
               const float* __restrict__ Lh_old, float* __restrict__ Lh_new,
               float* __restrict__ Lc,
               const float* __restrict__ Wt,     // [384][512] = [wih^T ; whh^T]
               const float* __restrict__ bih, const float* __restrict__ bhh){
  __shared__ __align__(16) float xs[8][384];   // [CL_msg | L_flip | h]
  __shared__ __align__(16) float gs[8][NG];
  int l0 = blockIdx.x*8;
  int tid = threadIdx.x;
  {
    int row = (tid & 255) >> 5, c4 = (tid & 31)*4;
    if (tid < 256){
      *(float4*)&xs[row][256 + c4] = *(const float4*)&Lh_old[(size_t)(l0+row)*DIM + c4];
    } else {
      int fl = (l0 + row + NV) & (NL-1);
      *(float4*)&xs[row][DIM + c4] = *(const float4*)&Lh_old[(size_t)fl*DIM + c4];
    }
  }
  {
    int j = tid & 127, rslot = tid >> 7;
#pragma unroll
    for (int rr = 0; rr < 2; ++rr){
      int r = rslot*2 + rr;
      int l = l0 + r;
      float s = 0.f;
      int n = cnt[l];
      const int* ls = lst + (size_t)l*LCAP;
      for (int t = 0; t < n; ++t) s += Cpre[(size_t)ls[t]*DIM + j];
      xs[r][j] = s;
    }
  }
  __syncthreads();
  int j4 = (tid & 127)*4, rowg = tid >> 7;
  int ra = rowg*2, rb = ra+1;
  float a0[4] = {0.f,0.f,0.f,0.f}, a1[4] = {0.f,0.f,0.f,0.f};
#pragma unroll 2
  for (int k = 0; k < 384; k += 4){
    float4 w0 = *(const float4*)&Wt[(size_t)(k+0)*NG + j4];
    float4 w1 = *(const float4*)&Wt[(size_t)(k+1)*NG + j4];
    float4 w2 = *(const float4*)&Wt[(size_t)(k+2)*NG + j4];
    float4 w3 = *(const float4*)&Wt[(size_t)(k+3)*NG + j4];
    float4 xa = *(const float4*)&xs[ra][k];
    float4 xb = *(const float4*)&xs[rb][k];
    a0[0] += xa.x*w0.x + xa.y*w1.x + xa.z*w2.x + xa.w*w3.x;
    a0[1] += xa.x*w0.y + xa.y*w1.y + xa.z*w2.y + xa.w*w3.y;
    a0[2] += xa.x*w0.z + xa.y*w1.z + xa.z*w2.z + xa.w*w3.z;
    a0[3] += xa.x*w0.w + xa.y*w1.w + xa.z*w2.w + xa.w*w3.w;
    a1[0] += xb.x*w0.x + xb.y*w1.x + xb.z*w2.x + xb.w*w3.x;
    a1[1] += xb.x*w0.y + xb.y*w1.y + xb.z*w2.y + xb.w*w3.y;
    a1[2] += xb.x*w0.z + xb.y*w1.z + xb.z*w2.z + xb.w*w3.z;
    a1[3] += xb.x*w0.w + xb.y*w1.w + xb.z*w2.w + xb.w*w3.w;
  }
  {
    float4 bi = *(const float4*)&bih[j4];
    float4 bh = *(const float4*)&bhh[j4];
    *(float4*)&gs[ra][j4] = make_float4(a0[0]+bi.x+bh.x, a0[1]+bi.y+bh.y,
                                        a0[2]+bi.z+bh.z, a0[3]+bi.w+bh.w);
    *(float4*)&gs[rb][j4] = make_float4(a1[0]+bi.x+bh.x, a1[1]+bi.y+bh.y,
                                        a1[2]+bi.z+bh.z, a1[3]+bi.w+bh.w);
  }
  __syncthreads();
#pragma unroll
  for (int i = 0; i < 2; ++i){
    int e = tid + i*512; int r = e >> 7, d = e & 127;
    float ig = gs[r][d], fg = gs[r][DIM+d], gg = gs[r][2*DIM+d], og = gs[r][3*DIM+d];
    size_t off = (size_t)(l0+r)*DIM + d;
    float cn = sigf(fg)*Lc[off] + sigf(ig)*tanhf(gg);
    float hn = sigf(og)*tanhf(cn);
    Lc[off] = cn;
    Lh_new[off] = hn;
  }
}

// ---- vote MLP (128->128->128->1), 8 rows/block -----------------------------
__global__ __launch_bounds__(256, 4)
void k_vote(const float* __restrict__ Lh, float* __restrict__ vote,
            float* __restrict__ dout,
            const float* __restrict__ w1t, const float* __restrict__ b1,
            const float* __restrict__ w2t, const float* __restrict__ b2,
            const float* __restrict__ w3, const float* __restrict__ b3){
  __shared__ __align__(16) float xs[8][DIM];
  __shared__ __align__(16) float ys[8][DIM];
  int r0 = blockIdx.x*8;
  int tid = threadIdx.x;
  {
    int row = tid >> 5, c4 = (tid & 31)*4;
    *(float4*)&xs[row][c4] = *(const float4*)&Lh[(size_t)(r0+row)*DIM + c4];
  }
  __syncthreads();
  mlp_layer8<true>(xs, ys, w1t, b1, tid);
  __syncthreads();
  mlp_layer8<true>(ys, xs, w2t, b2, tid);
  __syncthreads();
  int r = tid >> 5, lane32 = tid & 31;
  float4 x = *(const float4*)&xs[r][lane32*4];
  float4 w = *(const float4*)&w3[lane32*4];
  float pp = x.x*w.x + x.y*w.y + x.z*w.z + x.w*w.w;
  pp += __shfl_down(pp, 16, 32);
  pp += __shfl_down(pp, 8, 32);
  pp += __shfl_down(pp, 4, 32);
  pp += __shfl_down(pp, 2, 32);
  pp += __shfl_down(pp, 1, 32);
  if (lane32 == 0){
    float t = pp + b3[0];
    vote[r0+r] = t;
    dout[1 + r0 + r] = t;
  }
}

__global__ void k_copy_logits(const float* __restrict__ Lh, float* __restrict__ dout){
  int idx = blockIdx.x*blockDim.x + threadIdx.x;
  if (idx < NL*DIM) dout[1 + NL + idx] = Lh[idx];
}

__global__ void k_mean(const float* __restrict__ vote, float* __restrict__ dout){
  __shared__ float red[256];
  int tid = threadIdx.x;
  float s = 0.f;
  for (int i = tid; i < NL; i += 256) s += vote[i];
  red[tid] = s;
  __syncthreads();
  for (int w = 128; w > 0; w >>= 1){
    if (tid < w) red[tid] += red[tid+w];
    __syncthreads();
  }
  if (tid == 0) dout[0] = red[0] / (float)NL;
}

// ---- host ------------------------------------------------------------------
static inline void launch_transpose(const float* src, float* dst, int R, int C,
                                    hipStream_t stream){
  dim3 g((C+31)/32, (R+31)/32), b(32, 8);
  k_transpose<<<g, b, 0, stream>>>(src, dst, R, C);
}

extern "C" void kernel_launch(void* const* d_in, const int* in_sizes, int n_in,
                              void* d_out, int out_size, void* d_ws, size_t ws_size,
                              hipStream_t stream){
  const float* adj      = (const float*)d_in[0];
  const float* l_init_w = (const float*)d_in[1];
  const float* l_init_b = (const float*)d_in[2];
  const float* c_init_w = (const float*)d_in[3];
  const float* c_init_b = (const float*)d_in[4];
  const float* lmsg_w1  = (const float*)d_in[5];
  const float* lmsg_b1  = (const float*)d_in[6];
  const float* lmsg_w2  = (const float*)d_in[7];
  const float* lmsg_b2  = (const float*)d_in[8];
  const float* lmsg_w3  = (const float*)d_in[9];
  const float* lmsg_b3  = (const float*)d_in[10];
  const float* cmsg_w1  = (const float*)d_in[11];
  const float* cmsg_b1  = (const float*)d_in[12];
  const float* cmsg_w2  = (const float*)d_in[13];
  const float* cmsg_b2  = (const float*)d_in[14];
  const float* cmsg_w3  = (const float*)d_in[15];
  const float* cmsg_b3  = (const float*)d_in[16];
  const float* l_wih    = (const float*)d_in[17];
  const float* l_whh    = (const float*)d_in[18];
  const float* l_bih    = (const float*)d_in[19];
  const float* l_bhh    = (const float*)d_in[20];
  const float* c_wih    = (const float*)d_in[21];
  const float* c_whh    = (const float*)d_in[22];
  const float* c_bih    = (const float*)d_in[23];
  const float* c_bhh    = (const float*)d_in[24];
  const float* lvote_w1 = (const float*)d_in[25];
  const float* lvote_b1 = (const float*)d_in[26];
  const float* lvote_w2 = (const float*)d_in[27];
  const float* lvote_b2 = (const float*)d_in[28];
  const float* lvote_w3 = (const float*)d_in[29];
  const float* lvote_b3 = (const float*)d_in[30];

  char* p = (char*)d_ws;
  auto alloc = [&](size_t bytes) -> void* {
    void* r = (void*)p;
    p += (bytes + 255) & ~(size_t)255;
    return r;
  };
  float* LhA   = (float*)alloc((size_t)NL*DIM*4);
  float* LhB   = (float*)alloc((size_t)NL*DIM*4);
  float* Lc    = (float*)alloc((size_t)NL*DIM*4);
  float* Ch    = (float*)alloc((size_t)NC*DIM*4);
  float* Cc    = (float*)alloc((size_t)NC*DIM*4);
  float* Lpre  = (float*)alloc((size_t)NL*DIM*4);
  float* Cpre  = (float*)alloc((size_t)NC*DIM*4);
  float* vote  = (float*)alloc((size_t)NL*4);
  int* scnt_c  = (int*)alloc((size_t)NC*CSEG*4);
  int* slst_c  = (int*)alloc((size_t)NC*CSEG*CSEGCAP*4);
  int* scnt_l  = (int*)alloc((size_t)NL*LSEG*4);
  int* slst_l  = (int*)alloc((size_t)NL*LSEG*LSEGCAP*4);
  int* ccnt    = (int*)alloc((size_t)NC*4);
  int* clst    = (int*)alloc((size_t)NC*CCAP*4);
  int* lcnt    = (int*)alloc((size_t)NL*4);
  int* llst    = (int*)alloc((size_t)NL*LCAP*4);
  // transposed (k-major) weights
  float* lm1t  = (float*)alloc((size_t)DIM*DIM*4);
  float* lm2t  = (float*)alloc((size_t)DIM*DIM*4);
  float* lm3t  = (float*)alloc((size_t)DIM*DIM*4);
  float* cm1t  = (float*)alloc((size_t)DIM*DIM*4);
  float* cm2t  = (float*)alloc((size_t)DIM*DIM*4);
  float* cm3t  = (float*)alloc((size_t)DIM*DIM*4);
  float* vw1t  = (float*)alloc((size_t)DIM*DIM*4);
  float* vw2t  = (float*)alloc((size_t)DIM*DIM*4);
  float* WtC   = (float*)alloc((size_t)256*NG*4);   // [wih^T;whh^T] clause
  float* WtL   = (float*)alloc((size_t)384*NG*4);   // [wih^T;whh^T] literal
  (void)ws_size; (void)in_sizes; (void)n_in; (void)out_size;

  launch_transpose(lmsg_w1, lm1t, DIM, DIM, stream);
  launch_transpose(lmsg_w2, lm2t, DIM, DIM, stream);
  launch_transpose(lmsg_w3, lm3t, DIM, DIM, stream);
  launch_transpose(cmsg_w1, cm1t, DIM, DIM, stream);
  launch_transpose(cmsg_w2, cm2t, DIM, DIM, stream);
  launch_transpose(cmsg_w3, cm3t, DIM, DIM, stream);
  launch_transpose(lvote_w1, vw1t, DIM, DIM, stream);
  launch_transpose(lvote_w2, vw2t, DIM, DIM, stream);
  launch_transpose(c_wih, WtC,            NG, DIM, stream);
  launch_transpose(c_whh, WtC + 128*NG,   NG, DIM, stream);
  launch_transpose(l_wih, WtL,            NG, 2*DIM, stream);
  launch_transpose(l_whh, WtL + 256*NG,   NG, DIM, stream);

  k_build_cseg<<<NC*CSEG/256, 256, 0, stream>>>(adj, scnt_c, slst_c);
  k_build_lseg<<<NL*LSEG*64/256, 256, 0, stream>>>(adj, scnt_l, slst_l);
  k_merge_c<<<NC/256, 256, 0, stream>>>(scnt_c, slst_c, ccnt, clst);
  k_merge_l<<<NL/256, 256, 0, stream>>>(scnt_l, slst_l, lcnt, llst);
  k_init<<<NC*DIM/256, 256, 0, stream>>>(l_init_w, l_init_b, c_init_w, c_init_b,
                                         LhA, Lc, Ch, Cc);

  float* Lh_cur = LhA;
  float* Lh_nxt = LhB;
  for (int r = 0; r < NROUNDS; ++r){
    k_mlp3<<<NL/8, 256, 0, stream>>>(Lh_cur, Lpre,
                                     lm1t, lmsg_b1, lm2t, lmsg_b2, lm3t, lmsg_b3);
    k_clause_upd<<<NC/8, 512, 0, stream>>>(Lpre, ccnt, clst, Ch, Cc,
                                           WtC, c_bih, c_bhh);
    k_mlp3<<<NC/8, 256, 0, stream>>>(Ch, Cpre,
                                     cm1t, cmsg_b1, cm2t, cmsg_b2, cm3t, cmsg_b3);
    k_lit_upd<<<NL/8, 512, 0, stream>>>(Cpre, lcnt, llst, Lh_cur, Lh_nxt, Lc,
                                        WtL, l_bih, l_bhh);
    float* t = Lh_cur; Lh_cur = Lh_nxt; Lh_nxt = t;
  }

  k_vote<<<NL/8, 256, 0, stream>>>(Lh_cur, vote, (float*)d_out,
                                   vw1t, lvote_b1, vw2t, lvote_b2,
                                   lvote_w3, lvote_b3);
  k_copy_logits<<<(NL*DIM)/256, 256, 0, stream>>>(Lh_cur, (float*)d_out);
  k_mean<<<1, 256, 0, stream>>>(vote, (float*)d_out);
}